// Round 3
// baseline (235.857 us; speedup 1.0000x reference)
//
#include <hip/hip_runtime.h>
#include <math.h>

// Problem constants (from reference)
#define EMBED 1024
#define FFN_DIM 4096
#define TOKENS (8 * 2048)
#define EPS 1e-5f

typedef __attribute__((ext_vector_type(4))) float f32x4;

__device__ __forceinline__ void circuit_cvec(const float* p, float cv[4]) {
    float c0 = cosf(p[0]);
    float c1 = cosf(p[1]);
    float c2 = cosf(p[2]);
    float c3 = cosf(p[3]);
    cv[0] = c1 * c2 * c3;
    cv[1] = c0 * c1;
    cv[2] = c0 * c1 * c2;
    cv[3] = c0 * c1 * c2 * c3;
}

// ws layout (floats): [0,1024) attn | [1024,2048) u=b1+ffn | [2048,3072) E1=g1*g2
// | [3072,4096) E2=g2*u | [4096,4104) scal: {Sg1, Su, Sg12, Sg1u, Su2}

__global__ __launch_bounds__(64) void k_zero(float* __restrict__ scal) {
    if (threadIdx.x < 8) scal[threadIdx.x] = 0.f;
}

// --- k_const: one block computes h[4096] in LDS, then 4 waves -> 4 output
// elements e; writes attn[e], u[e], E1[e], E2[e]; atomic-accumulates the 5
// token-independent scalars.
__global__ __launch_bounds__(256) void k_const(const float* __restrict__ w_mix,
                                               const float* __restrict__ attn_p,
                                               const float* __restrict__ w2,
                                               const float* __restrict__ w_out,
                                               const float* __restrict__ ffn_p,
                                               const float* __restrict__ g1v,
                                               const float* __restrict__ b1v,
                                               const float* __restrict__ g2v,
                                               const float* __restrict__ b2v,
                                               float* __restrict__ ws) {
    __shared__ float h[FFN_DIM];
    int tid = threadIdx.x;
    float cvf[4], cva[4];
    circuit_cvec(ffn_p, cvf);
    circuit_cvec(attn_p, cva);

    // h[f] = relu(dot4(w2[f], cvf)); coalesced: f = i*256 + tid
    #pragma unroll
    for (int i = 0; i < 16; ++i) {
        int f = i * 256 + tid;
        f32x4 r = *(const f32x4*)(w2 + f * 4);
        float s = r.x * cvf[0] + r.y * cvf[1] + r.z * cvf[2] + r.w * cvf[3];
        h[f] = s > 0.f ? s : 0.f;
    }
    __syncthreads();

    int e = blockIdx.x * 4 + (tid >> 6);
    int lane = tid & 63;

    // attn dot over w_mix row (1024): chunk c at c*256 + lane*4 (idx%4==0 -> cv[k])
    float sa = 0.f;
    const float* wm = w_mix + e * EMBED;
    #pragma unroll
    for (int c = 0; c < 4; ++c) {
        int idx = c * 256 + lane * 4;
        f32x4 v = *(const f32x4*)(wm + idx);
        sa += v.x * cva[0] + v.y * cva[1] + v.z * cva[2] + v.w * cva[3];
    }

    // ffn dot over w_out row (4096) x h
    float sf = 0.f;
    const float* wo = w_out + e * FFN_DIM;
    #pragma unroll
    for (int c = 0; c < 16; ++c) {
        int idx = c * 256 + lane * 4;
        f32x4 v = *(const f32x4*)(wo + idx);
        f32x4 hv = *(const f32x4*)(h + idx);
        sf += v.x * hv.x + v.y * hv.y + v.z * hv.z + v.w * hv.w;
    }

    #pragma unroll
    for (int m = 32; m >= 1; m >>= 1) {
        sa += __shfl_xor(sa, m, 64);
        sf += __shfl_xor(sf, m, 64);
    }

    if (lane == 0) {
        float g1 = g1v[e], b1 = b1v[e], g2 = g2v[e], b2 = b2v[e];
        float u = b1 + sf;
        ws[e] = sa;               // attn
        ws[1024 + e] = u;         // u
        ws[2048 + e] = g1 * g2;   // E1
        ws[3072 + e] = g2 * u;    // E2
        float* scal = ws + 4096;
        atomicAdd(scal + 0, g1);
        atomicAdd(scal + 1, u);
        atomicAdd(scal + 2, g1 * g1);
        atomicAdd(scal + 3, g1 * u);
        atomicAdd(scal + 4, u * u);
    }
}

// --- k_main: one wave per token. Single shuffle round; LN2 stats closed-form.
__global__ __launch_bounds__(256) void k_main(const float* __restrict__ x,
                                              const float* __restrict__ g1v,
                                              const float* __restrict__ g2v,
                                              const float* __restrict__ b2v,
                                              const float* __restrict__ ws,
                                              float* __restrict__ out) {
    int token = blockIdx.x * 4 + (threadIdx.x >> 6);
    int lane = threadIdx.x & 63;
    const int base = token * EMBED;

    const float* attn = ws;
    const float* uvec = ws + 1024;
    const float* E1v = ws + 2048;
    const float* E2v = ws + 3072;
    const float* scal = ws + 4096;
    float Sg1 = scal[0], Su = scal[1], Sg12 = scal[2], Sg1u = scal[3], Su2 = scal[4];

    // pass 1: y = x + attn; w = g1*y. Accumulate 6 moments.
    float y[16];
    float s = 0.f, s2 = 0.f, p = 0.f, p2 = 0.f, q = 0.f, pu = 0.f;
    #pragma unroll
    for (int c = 0; c < 4; ++c) {
        int off = c * 256 + lane * 4;
        f32x4 xv = *(const f32x4*)(x + base + off);
        f32x4 av = *(const f32x4*)(attn + off);
        f32x4 gv = *(const f32x4*)(g1v + off);
        f32x4 uv = *(const f32x4*)(uvec + off);
        #pragma unroll
        for (int k = 0; k < 4; ++k) {
            float yy = xv[k] + av[k];
            float w = gv[k] * yy;
            y[c * 4 + k] = yy;
            s += yy;
            s2 = fmaf(yy, yy, s2);
            p += w;
            p2 = fmaf(w, w, p2);
            q = fmaf(gv[k], w, q);
            pu = fmaf(w, uv[k], pu);
        }
    }

    // single reduction round: 6 values
    #pragma unroll
    for (int m = 32; m >= 1; m >>= 1) {
        s += __shfl_xor(s, m, 64);
        s2 += __shfl_xor(s2, m, 64);
        p += __shfl_xor(p, m, 64);
        p2 += __shfl_xor(p2, m, 64);
        q += __shfl_xor(q, m, 64);
        pu += __shfl_xor(pu, m, 64);
    }

    const float rN = 1.f / EMBED;
    float m1 = s * rN;
    float rs1 = rsqrtf(s2 * rN - m1 * m1 + EPS);
    // z = rs1*(w - m1*g1) + u
    float t = rs1 * (p - m1 * Sg1) + Su;
    float t2 = rs1 * rs1 * (p2 - 2.f * m1 * q + m1 * m1 * Sg12)
             + 2.f * rs1 * (pu - m1 * Sg1u) + Su2;
    float m2 = t * rN;
    float rs2 = rsqrtf(t2 * rN - m2 * m2 + EPS);

    // out = (rs1*rs2)*E1*(y - m1) + rs2*E2 - (m2*rs2)*g2 + b2
    float A = rs1 * rs2;
    float B = m2 * rs2;
    #pragma unroll
    for (int c = 0; c < 4; ++c) {
        int off = c * 256 + lane * 4;
        f32x4 e1 = *(const f32x4*)(E1v + off);
        f32x4 e2 = *(const f32x4*)(E2v + off);
        f32x4 g2 = *(const f32x4*)(g2v + off);
        f32x4 b2 = *(const f32x4*)(b2v + off);
        f32x4 o;
        #pragma unroll
        for (int k = 0; k < 4; ++k) {
            float base2 = fmaf(rs2, e2[k], fmaf(-B, g2[k], b2[k]));
            o[k] = fmaf(A * e1[k], y[c * 4 + k] - m1, base2);
        }
        __builtin_nontemporal_store(o, (f32x4*)(out + base + off));
    }
}

extern "C" void kernel_launch(void* const* d_in, const int* in_sizes, int n_in,
                              void* d_out, int out_size, void* d_ws, size_t ws_size,
                              hipStream_t stream) {
    // 0:x 1:wq 2:wk 3:wv 4:w_mix 5:attn_params 6:w1 7:w2 8:w_out 9:ffn_params
    // 10:ln1_g 11:ln1_b 12:ln2_g 13:ln2_b
    const float* x      = (const float*)d_in[0];
    const float* w_mix  = (const float*)d_in[4];
    const float* attn_p = (const float*)d_in[5];
    const float* w2     = (const float*)d_in[7];
    const float* w_out  = (const float*)d_in[8];
    const float* ffn_p  = (const float*)d_in[9];
    const float* ln1_g  = (const float*)d_in[10];
    const float* ln1_b  = (const float*)d_in[11];
    const float* ln2_g  = (const float*)d_in[12];
    const float* ln2_b  = (const float*)d_in[13];
    float* out = (float*)d_out;
    float* ws  = (float*)d_ws;

    k_zero<<<1, 64, 0, stream>>>(ws + 4096);
    k_const<<<EMBED / 4, 256, 0, stream>>>(w_mix, attn_p, w2, w_out, ffn_p,
                                           ln1_g, ln1_b, ln2_g, ln2_b, ws);
    k_main<<<TOKENS / 4, 256, 0, stream>>>(x, ln1_g, ln2_g, ln2_b, ws, out);
}

// Round 4
// 233.668 us; speedup vs baseline: 1.0094x; 1.0094x over previous
//
#include <hip/hip_runtime.h>
#include <math.h>

// Problem constants (from reference)
#define EMBED 1024
#define FFN_DIM 4096
#define TOKENS (8 * 2048)
#define EPS 1e-5f

typedef __attribute__((ext_vector_type(4))) float f32x4;

__device__ __forceinline__ void circuit_cvec(const float* p, float cv[4]) {
    float c0 = cosf(p[0]);
    float c1 = cosf(p[1]);
    float c2 = cosf(p[2]);
    float c3 = cosf(p[3]);
    cv[0] = c1 * c2 * c3;
    cv[1] = c0 * c1;
    cv[2] = c0 * c1 * c2;
    cv[3] = c0 * c1 * c2 * c3;
}

// ws layout (floats): [0,1024) attn | [1024,2048) u=b1+ffn | [2048,3072) E1=g1*g2
// | [3072,4096) E2=g2*u | [4096,4104) scal {Sg1,Su,Sg12,Sg1u,Su2} | [4224,8320) h

__global__ __launch_bounds__(64) void k_zero(float* __restrict__ scal) {
    if (threadIdx.x < 8) scal[threadIdx.x] = 0.f;
}

// --- k_hidden: h[f] = relu(dot4(w2[f], cvec_f)), 16 blocks x 256 ---
__global__ __launch_bounds__(256) void k_hidden(const float* __restrict__ w2,
                                                const float* __restrict__ ffn_p,
                                                float* __restrict__ h) {
    int f = blockIdx.x * 256 + threadIdx.x;
    float cv[4];
    circuit_cvec(ffn_p, cv);
    f32x4 r = *(const f32x4*)(w2 + f * 4);
    float s = r.x * cv[0] + r.y * cv[1] + r.z * cv[2] + r.w * cv[3];
    h[f] = s > 0.f ? s : 0.f;
}

// --- k_const: one wave per output element e in [0,1024). Writes attn[e], u[e],
// E1[e], E2[e]; atomic-accumulates 5 token-independent scalars.
__global__ __launch_bounds__(256) void k_const(const float* __restrict__ w_mix,
                                               const float* __restrict__ attn_p,
                                               const float* __restrict__ w_out,
                                               const float* __restrict__ g1v,
                                               const float* __restrict__ b1v,
                                               const float* __restrict__ g2v,
                                               const float* __restrict__ b2v,
                                               float* __restrict__ ws) {
    int e = blockIdx.x * 4 + (threadIdx.x >> 6);
    int lane = threadIdx.x & 63;
    const float* h = ws + 4224;
    float cva[4];
    circuit_cvec(attn_p, cva);

    // attn dot over w_mix row (1024): lane-contiguous float4, idx%4==0 -> cv[k]
    float sa = 0.f;
    const float* wm = w_mix + e * EMBED;
    #pragma unroll
    for (int c = 0; c < 4; ++c) {
        int idx = c * 256 + lane * 4;
        f32x4 v = *(const f32x4*)(wm + idx);
        sa += v.x * cva[0] + v.y * cva[1] + v.z * cva[2] + v.w * cva[3];
    }

    // ffn dot over w_out row (4096) x h (L2-resident)
    float sf = 0.f;
    const float* wo = w_out + e * FFN_DIM;
    #pragma unroll
    for (int c = 0; c < 16; ++c) {
        int idx = c * 256 + lane * 4;
        f32x4 v = *(const f32x4*)(wo + idx);
        f32x4 hv = *(const f32x4*)(h + idx);
        sf += v.x * hv.x + v.y * hv.y + v.z * hv.z + v.w * hv.w;
    }

    #pragma unroll
    for (int m = 32; m >= 1; m >>= 1) {
        sa += __shfl_xor(sa, m, 64);
        sf += __shfl_xor(sf, m, 64);
    }

    if (lane == 0) {
        float g1 = g1v[e], b1 = b1v[e], g2 = g2v[e];
        float u = b1 + sf;
        ws[e] = sa;               // attn
        ws[1024 + e] = u;         // u
        ws[2048 + e] = g1 * g2;   // E1
        ws[3072 + e] = g2 * u;    // E2
        float* scal = ws + 4096;
        atomicAdd(scal + 0, g1);
        atomicAdd(scal + 1, u);
        atomicAdd(scal + 2, g1 * g1);
        atomicAdd(scal + 3, g1 * u);
        atomicAdd(scal + 4, u * u);
    }
}

// --- k_main: one wave per 2 tokens; single shuffle round for 12 moments. ---
__global__ __launch_bounds__(256) void k_main(const float* __restrict__ x,
                                              const float* __restrict__ g1v,
                                              const float* __restrict__ g2v,
                                              const float* __restrict__ b2v,
                                              const float* __restrict__ ws,
                                              float* __restrict__ out) {
    int pair = blockIdx.x * 4 + (threadIdx.x >> 6);  // wave id
    int lane = threadIdx.x & 63;
    const int base0 = (pair * 2) * EMBED;
    const int base1 = base0 + EMBED;

    const float* attn = ws;
    const float* uvec = ws + 1024;
    const float* E1v = ws + 2048;
    const float* E2v = ws + 3072;
    const float* scal = ws + 4096;
    float Sg1 = scal[0], Su = scal[1], Sg12 = scal[2], Sg1u = scal[3], Su2 = scal[4];

    // pass 1 (both tokens): y = x + attn; w = g1*y; 6 moments each.
    float y0[16], y1[16];
    float s_0 = 0.f, s2_0 = 0.f, p_0 = 0.f, p2_0 = 0.f, q_0 = 0.f, pu_0 = 0.f;
    float s_1 = 0.f, s2_1 = 0.f, p_1 = 0.f, p2_1 = 0.f, q_1 = 0.f, pu_1 = 0.f;
    #pragma unroll
    for (int c = 0; c < 4; ++c) {
        int off = c * 256 + lane * 4;
        f32x4 xv0 = *(const f32x4*)(x + base0 + off);
        f32x4 xv1 = *(const f32x4*)(x + base1 + off);
        f32x4 av = *(const f32x4*)(attn + off);
        f32x4 gv = *(const f32x4*)(g1v + off);
        f32x4 uv = *(const f32x4*)(uvec + off);
        #pragma unroll
        for (int k = 0; k < 4; ++k) {
            float yy0 = xv0[k] + av[k];
            float yy1 = xv1[k] + av[k];
            float w0 = gv[k] * yy0;
            float w1 = gv[k] * yy1;
            y0[c * 4 + k] = yy0;
            y1[c * 4 + k] = yy1;
            s_0 += yy0;            s_1 += yy1;
            s2_0 = fmaf(yy0, yy0, s2_0);  s2_1 = fmaf(yy1, yy1, s2_1);
            p_0 += w0;             p_1 += w1;
            p2_0 = fmaf(w0, w0, p2_0);    p2_1 = fmaf(w1, w1, p2_1);
            q_0 = fmaf(gv[k], w0, q_0);   q_1 = fmaf(gv[k], w1, q_1);
            pu_0 = fmaf(w0, uv[k], pu_0); pu_1 = fmaf(w1, uv[k], pu_1);
        }
    }

    // one reduction round, 12 values
    #pragma unroll
    for (int m = 32; m >= 1; m >>= 1) {
        s_0 += __shfl_xor(s_0, m, 64);   s_1 += __shfl_xor(s_1, m, 64);
        s2_0 += __shfl_xor(s2_0, m, 64); s2_1 += __shfl_xor(s2_1, m, 64);
        p_0 += __shfl_xor(p_0, m, 64);   p_1 += __shfl_xor(p_1, m, 64);
        p2_0 += __shfl_xor(p2_0, m, 64); p2_1 += __shfl_xor(p2_1, m, 64);
        q_0 += __shfl_xor(q_0, m, 64);   q_1 += __shfl_xor(q_1, m, 64);
        pu_0 += __shfl_xor(pu_0, m, 64); pu_1 += __shfl_xor(pu_1, m, 64);
    }

    const float rN = 1.f / EMBED;
    float m1_0 = s_0 * rN;
    float m1_1 = s_1 * rN;
    float rs1_0 = rsqrtf(s2_0 * rN - m1_0 * m1_0 + EPS);
    float rs1_1 = rsqrtf(s2_1 * rN - m1_1 * m1_1 + EPS);
    float t_0 = rs1_0 * (p_0 - m1_0 * Sg1) + Su;
    float t_1 = rs1_1 * (p_1 - m1_1 * Sg1) + Su;
    float t2_0 = rs1_0 * rs1_0 * (p2_0 - 2.f * m1_0 * q_0 + m1_0 * m1_0 * Sg12)
               + 2.f * rs1_0 * (pu_0 - m1_0 * Sg1u) + Su2;
    float t2_1 = rs1_1 * rs1_1 * (p2_1 - 2.f * m1_1 * q_1 + m1_1 * m1_1 * Sg12)
               + 2.f * rs1_1 * (pu_1 - m1_1 * Sg1u) + Su2;
    float m2_0 = t_0 * rN;
    float m2_1 = t_1 * rN;
    float rs2_0 = rsqrtf(t2_0 * rN - m2_0 * m2_0 + EPS);
    float rs2_1 = rsqrtf(t2_1 * rN - m2_1 * m2_1 + EPS);

    float A0 = rs1_0 * rs2_0, B0 = m2_0 * rs2_0;
    float A1 = rs1_1 * rs2_1, B1 = m2_1 * rs2_1;

    #pragma unroll
    for (int c = 0; c < 4; ++c) {
        int off = c * 256 + lane * 4;
        f32x4 e1 = *(const f32x4*)(E1v + off);
        f32x4 e2 = *(const f32x4*)(E2v + off);
        f32x4 g2 = *(const f32x4*)(g2v + off);
        f32x4 b2 = *(const f32x4*)(b2v + off);
        f32x4 o0, o1;
        #pragma unroll
        for (int k = 0; k < 4; ++k) {
            float c0 = fmaf(rs2_0, e2[k], fmaf(-B0, g2[k], b2[k]));
            float c1 = fmaf(rs2_1, e2[k], fmaf(-B1, g2[k], b2[k]));
            o0[k] = fmaf(A0 * e1[k], y0[c * 4 + k] - m1_0, c0);
            o1[k] = fmaf(A1 * e1[k], y1[c * 4 + k] - m1_1, c1);
        }
        __builtin_nontemporal_store(o0, (f32x4*)(out + base0 + off));
        __builtin_nontemporal_store(o1, (f32x4*)(out + base1 + off));
    }
}

extern "C" void kernel_launch(void* const* d_in, const int* in_sizes, int n_in,
                              void* d_out, int out_size, void* d_ws, size_t ws_size,
                              hipStream_t stream) {
    // 0:x 1:wq 2:wk 3:wv 4:w_mix 5:attn_params 6:w1 7:w2 8:w_out 9:ffn_params
    // 10:ln1_g 11:ln1_b 12:ln2_g 13:ln2_b
    const float* x      = (const float*)d_in[0];
    const float* w_mix  = (const float*)d_in[4];
    const float* attn_p = (const float*)d_in[5];
    const float* w2     = (const float*)d_in[7];
    const float* w_out  = (const float*)d_in[8];
    const float* ffn_p  = (const float*)d_in[9];
    const float* ln1_g  = (const float*)d_in[10];
    const float* ln1_b  = (const float*)d_in[11];
    const float* ln2_g  = (const float*)d_in[12];
    const float* ln2_b  = (const float*)d_in[13];
    float* out = (float*)d_out;
    float* ws  = (float*)d_ws;

    k_zero<<<1, 64, 0, stream>>>(ws + 4096);
    k_hidden<<<FFN_DIM / 256, 256, 0, stream>>>(w2, ffn_p, ws + 4224);
    k_const<<<EMBED / 4, 256, 0, stream>>>(w_mix, attn_p, w_out,
                                           ln1_g, ln1_b, ln2_g, ln2_b, ws);
    k_main<<<TOKENS / 8, 256, 0, stream>>>(x, ln1_g, ln2_g, ln2_b, ws, out);
}

// Round 5
// 167.044 us; speedup vs baseline: 1.4119x; 1.3988x over previous
//
#include <hip/hip_runtime.h>
#include <math.h>

// Problem constants (from reference)
#define EMBED 1024
#define FFN_DIM 4096
#define TOKENS (8 * 2048)
#define EPS 1e-5f

typedef __attribute__((ext_vector_type(4))) float f32x4;

__device__ __forceinline__ void circuit_cvec(const float* p, float cv[4]) {
    float c0 = cosf(p[0]);
    float c1 = cosf(p[1]);
    float c2 = cosf(p[2]);
    float c3 = cosf(p[3]);
    cv[0] = c1 * c2 * c3;
    cv[1] = c0 * c1;
    cv[2] = c0 * c1 * c2;
    cv[3] = c0 * c1 * c2 * c3;
}

// ws layout (floats): [0,1024) attn | [1024,2048) u=b1+ffn | [2048,3072) E1=g1*g2
// | [3072,4096) E2=g2*u | [4224,8320) h

// --- k_hidden: h[f] = relu(dot4(w2[f], cvec_f)), 16 blocks x 256 ---
__global__ __launch_bounds__(256) void k_hidden(const float* __restrict__ w2,
                                                const float* __restrict__ ffn_p,
                                                float* __restrict__ h) {
    int f = blockIdx.x * 256 + threadIdx.x;
    float cv[4];
    circuit_cvec(ffn_p, cv);
    f32x4 r = *(const f32x4*)(w2 + f * 4);
    float s = r.x * cv[0] + r.y * cv[1] + r.z * cv[2] + r.w * cv[3];
    h[f] = s > 0.f ? s : 0.f;
}

// --- k_const: one wave per output element e in [0,1024). Writes attn[e], u[e],
// E1[e], E2[e]. NO atomics (the 5 global scalars are computed in k_main).
__global__ __launch_bounds__(256) void k_const(const float* __restrict__ w_mix,
                                               const float* __restrict__ attn_p,
                                               const float* __restrict__ w_out,
                                               const float* __restrict__ g1v,
                                               const float* __restrict__ b1v,
                                               const float* __restrict__ g2v,
                                               float* __restrict__ ws) {
    int e = blockIdx.x * 4 + (threadIdx.x >> 6);
    int lane = threadIdx.x & 63;
    const float* h = ws + 4224;
    float cva[4];
    circuit_cvec(attn_p, cva);

    // attn dot over w_mix row (1024): lane-contiguous float4, idx%4==0 -> cv[k]
    float sa = 0.f;
    const float* wm = w_mix + e * EMBED;
    #pragma unroll
    for (int c = 0; c < 4; ++c) {
        int idx = c * 256 + lane * 4;
        f32x4 v = *(const f32x4*)(wm + idx);
        sa += v.x * cva[0] + v.y * cva[1] + v.z * cva[2] + v.w * cva[3];
    }

    // ffn dot over w_out row (4096) x h (cache-resident)
    float sf = 0.f;
    const float* wo = w_out + e * FFN_DIM;
    #pragma unroll
    for (int c = 0; c < 16; ++c) {
        int idx = c * 256 + lane * 4;
        f32x4 v = *(const f32x4*)(wo + idx);
        f32x4 hv = *(const f32x4*)(h + idx);
        sf += v.x * hv.x + v.y * hv.y + v.z * hv.z + v.w * hv.w;
    }

    #pragma unroll
    for (int m = 32; m >= 1; m >>= 1) {
        sa += __shfl_xor(sa, m, 64);
        sf += __shfl_xor(sf, m, 64);
    }

    if (lane == 0) {
        float g1 = g1v[e], b1 = b1v[e], g2 = g2v[e];
        float u = b1 + sf;
        ws[e] = sa;               // attn
        ws[1024 + e] = u;         // u
        ws[2048 + e] = g1 * g2;   // E1
        ws[3072 + e] = g2 * u;    // E2
    }
}

// --- k_main: one wave per 2 tokens. Single shuffle round (17 values):
// 12 per-token moments + 5 token-independent scalars computed redundantly
// from g1/u which the wave already loads (covers all 1024 elements).
__global__ __launch_bounds__(256) void k_main(const float* __restrict__ x,
                                              const float* __restrict__ g1v,
                                              const float* __restrict__ g2v,
                                              const float* __restrict__ b2v,
                                              const float* __restrict__ ws,
                                              float* __restrict__ out) {
    int pair = blockIdx.x * 4 + (threadIdx.x >> 6);  // wave id
    int lane = threadIdx.x & 63;
    const int base0 = (pair * 2) * EMBED;
    const int base1 = base0 + EMBED;

    const float* attn = ws;
    const float* uvec = ws + 1024;
    const float* E1v = ws + 2048;
    const float* E2v = ws + 3072;

    // pass 1 (both tokens): y = x + attn; w = g1*y; 6 moments each +
    // 5 scalar sums over g1/u.
    float y0[16], y1[16];
    float s_0 = 0.f, s2_0 = 0.f, p_0 = 0.f, p2_0 = 0.f, q_0 = 0.f, pu_0 = 0.f;
    float s_1 = 0.f, s2_1 = 0.f, p_1 = 0.f, p2_1 = 0.f, q_1 = 0.f, pu_1 = 0.f;
    float sg = 0.f, su = 0.f, sg2 = 0.f, sgu = 0.f, su2 = 0.f;
    #pragma unroll
    for (int c = 0; c < 4; ++c) {
        int off = c * 256 + lane * 4;
        f32x4 xv0 = __builtin_nontemporal_load((const f32x4*)(x + base0 + off));
        f32x4 xv1 = __builtin_nontemporal_load((const f32x4*)(x + base1 + off));
        f32x4 av = *(const f32x4*)(attn + off);
        f32x4 gv = *(const f32x4*)(g1v + off);
        f32x4 uv = *(const f32x4*)(uvec + off);
        #pragma unroll
        for (int k = 0; k < 4; ++k) {
            float yy0 = xv0[k] + av[k];
            float yy1 = xv1[k] + av[k];
            float w0 = gv[k] * yy0;
            float w1 = gv[k] * yy1;
            y0[c * 4 + k] = yy0;
            y1[c * 4 + k] = yy1;
            s_0 += yy0;            s_1 += yy1;
            s2_0 = fmaf(yy0, yy0, s2_0);  s2_1 = fmaf(yy1, yy1, s2_1);
            p_0 += w0;             p_1 += w1;
            p2_0 = fmaf(w0, w0, p2_0);    p2_1 = fmaf(w1, w1, p2_1);
            q_0 = fmaf(gv[k], w0, q_0);   q_1 = fmaf(gv[k], w1, q_1);
            pu_0 = fmaf(w0, uv[k], pu_0); pu_1 = fmaf(w1, uv[k], pu_1);
            sg += gv[k];
            su += uv[k];
            sg2 = fmaf(gv[k], gv[k], sg2);
            sgu = fmaf(gv[k], uv[k], sgu);
            su2 = fmaf(uv[k], uv[k], su2);
        }
    }

    // one reduction round, 17 values
    #pragma unroll
    for (int m = 32; m >= 1; m >>= 1) {
        s_0 += __shfl_xor(s_0, m, 64);   s_1 += __shfl_xor(s_1, m, 64);
        s2_0 += __shfl_xor(s2_0, m, 64); s2_1 += __shfl_xor(s2_1, m, 64);
        p_0 += __shfl_xor(p_0, m, 64);   p_1 += __shfl_xor(p_1, m, 64);
        p2_0 += __shfl_xor(p2_0, m, 64); p2_1 += __shfl_xor(p2_1, m, 64);
        q_0 += __shfl_xor(q_0, m, 64);   q_1 += __shfl_xor(q_1, m, 64);
        pu_0 += __shfl_xor(pu_0, m, 64); pu_1 += __shfl_xor(pu_1, m, 64);
        sg += __shfl_xor(sg, m, 64);
        su += __shfl_xor(su, m, 64);
        sg2 += __shfl_xor(sg2, m, 64);
        sgu += __shfl_xor(sgu, m, 64);
        su2 += __shfl_xor(su2, m, 64);
    }
    float Sg1 = sg, Su = su, Sg12 = sg2, Sg1u = sgu, Su2 = su2;

    const float rN = 1.f / EMBED;
    float m1_0 = s_0 * rN;
    float m1_1 = s_1 * rN;
    float rs1_0 = rsqrtf(s2_0 * rN - m1_0 * m1_0 + EPS);
    float rs1_1 = rsqrtf(s2_1 * rN - m1_1 * m1_1 + EPS);
    float t_0 = rs1_0 * (p_0 - m1_0 * Sg1) + Su;
    float t_1 = rs1_1 * (p_1 - m1_1 * Sg1) + Su;
    float t2_0 = rs1_0 * rs1_0 * (p2_0 - 2.f * m1_0 * q_0 + m1_0 * m1_0 * Sg12)
               + 2.f * rs1_0 * (pu_0 - m1_0 * Sg1u) + Su2;
    float t2_1 = rs1_1 * rs1_1 * (p2_1 - 2.f * m1_1 * q_1 + m1_1 * m1_1 * Sg12)
               + 2.f * rs1_1 * (pu_1 - m1_1 * Sg1u) + Su2;
    float m2_0 = t_0 * rN;
    float m2_1 = t_1 * rN;
    float rs2_0 = rsqrtf(t2_0 * rN - m2_0 * m2_0 + EPS);
    float rs2_1 = rsqrtf(t2_1 * rN - m2_1 * m2_1 + EPS);

    float A0 = rs1_0 * rs2_0, B0 = m2_0 * rs2_0;
    float A1 = rs1_1 * rs2_1, B1 = m2_1 * rs2_1;

    #pragma unroll
    for (int c = 0; c < 4; ++c) {
        int off = c * 256 + lane * 4;
        f32x4 e1 = *(const f32x4*)(E1v + off);
        f32x4 e2 = *(const f32x4*)(E2v + off);
        f32x4 g2 = *(const f32x4*)(g2v + off);
        f32x4 b2 = *(const f32x4*)(b2v + off);
        f32x4 o0, o1;
        #pragma unroll
        for (int k = 0; k < 4; ++k) {
            float c0 = fmaf(rs2_0, e2[k], fmaf(-B0, g2[k], b2[k]));
            float c1 = fmaf(rs2_1, e2[k], fmaf(-B1, g2[k], b2[k]));
            o0[k] = fmaf(A0 * e1[k], y0[c * 4 + k] - m1_0, c0);
            o1[k] = fmaf(A1 * e1[k], y1[c * 4 + k] - m1_1, c1);
        }
        __builtin_nontemporal_store(o0, (f32x4*)(out + base0 + off));
        __builtin_nontemporal_store(o1, (f32x4*)(out + base1 + off));
    }
}

extern "C" void kernel_launch(void* const* d_in, const int* in_sizes, int n_in,
                              void* d_out, int out_size, void* d_ws, size_t ws_size,
                              hipStream_t stream) {
    // 0:x 1:wq 2:wk 3:wv 4:w_mix 5:attn_params 6:w1 7:w2 8:w_out 9:ffn_params
    // 10:ln1_g 11:ln1_b 12:ln2_g 13:ln2_b
    const float* x      = (const float*)d_in[0];
    const float* w_mix  = (const float*)d_in[4];
    const float* attn_p = (const float*)d_in[5];
    const float* w2     = (const float*)d_in[7];
    const float* w_out  = (const float*)d_in[8];
    const float* ffn_p  = (const float*)d_in[9];
    const float* ln1_g  = (const float*)d_in[10];
    const float* ln1_b  = (const float*)d_in[11];
    const float* ln2_g  = (const float*)d_in[12];
    const float* ln2_b  = (const float*)d_in[13];
    float* out = (float*)d_out;
    float* ws  = (float*)d_ws;

    k_hidden<<<FFN_DIM / 256, 256, 0, stream>>>(w2, ffn_p, ws + 4224);
    k_const<<<EMBED / 4, 256, 0, stream>>>(w_mix, attn_p, w_out,
                                           ln1_g, ln1_b, ln2_g, ws);
    k_main<<<TOKENS / 8, 256, 0, stream>>>(x, ln1_g, ln2_g, ln2_b, ws, out);
}

// Round 6
// 162.452 us; speedup vs baseline: 1.4519x; 1.0283x over previous
//
#include <hip/hip_runtime.h>
#include <math.h>

// Problem constants (from reference)
#define EMBED 1024
#define FFN_DIM 4096
#define TOKENS (8 * 2048)
#define EPS 1e-5f

typedef __attribute__((ext_vector_type(4))) float f32x4;

__device__ __forceinline__ void circuit_cvec(const float* p, float cv[4]) {
    float c0 = cosf(p[0]);
    float c1 = cosf(p[1]);
    float c2 = cosf(p[2]);
    float c3 = cosf(p[3]);
    cv[0] = c1 * c2 * c3;
    cv[1] = c0 * c1;
    cv[2] = c0 * c1 * c2;
    cv[3] = c0 * c1 * c2 * c3;
}

// ws layout (floats): [0,1024) attn | [1024,2048) u=b1+ffn | [2048,3072) E1=g1*g2
// | [3072,4096) E2=g2*u | [4224,8320) h

// --- k_hidden: h[f] = relu(dot4(w2[f], cvec_f)), 16 blocks x 256 ---
__global__ __launch_bounds__(256) void k_hidden(const float* __restrict__ w2,
                                                const float* __restrict__ ffn_p,
                                                float* __restrict__ h) {
    int f = blockIdx.x * 256 + threadIdx.x;
    float cv[4];
    circuit_cvec(ffn_p, cv);
    f32x4 r = *(const f32x4*)(w2 + f * 4);
    float s = r.x * cv[0] + r.y * cv[1] + r.z * cv[2] + r.w * cv[3];
    h[f] = s > 0.f ? s : 0.f;
}

// --- k_const: one wave per output element e in [0,1024). Writes attn[e], u[e],
// E1[e], E2[e]. No atomics (global scalars are recomputed per-wave in k_main).
__global__ __launch_bounds__(256) void k_const(const float* __restrict__ w_mix,
                                               const float* __restrict__ attn_p,
                                               const float* __restrict__ w_out,
                                               const float* __restrict__ g1v,
                                               const float* __restrict__ b1v,
                                               const float* __restrict__ g2v,
                                               float* __restrict__ ws) {
    int e = blockIdx.x * 4 + (threadIdx.x >> 6);
    int lane = threadIdx.x & 63;
    const float* h = ws + 4224;
    float cva[4];
    circuit_cvec(attn_p, cva);

    float sa = 0.f;
    const float* wm = w_mix + e * EMBED;
    #pragma unroll
    for (int c = 0; c < 4; ++c) {
        int idx = c * 256 + lane * 4;
        f32x4 v = *(const f32x4*)(wm + idx);
        sa += v.x * cva[0] + v.y * cva[1] + v.z * cva[2] + v.w * cva[3];
    }

    float sf = 0.f;
    const float* wo = w_out + e * FFN_DIM;
    #pragma unroll
    for (int c = 0; c < 16; ++c) {
        int idx = c * 256 + lane * 4;
        f32x4 v = *(const f32x4*)(wo + idx);
        f32x4 hv = *(const f32x4*)(h + idx);
        sf += v.x * hv.x + v.y * hv.y + v.z * hv.z + v.w * hv.w;
    }

    #pragma unroll
    for (int m = 32; m >= 1; m >>= 1) {
        sa += __shfl_xor(sa, m, 64);
        sf += __shfl_xor(sf, m, 64);
    }

    if (lane == 0) {
        float g1 = g1v[e], b1 = b1v[e], g2 = g2v[e];
        float u = b1 + sf;
        ws[e] = sa;               // attn
        ws[1024 + e] = u;         // u
        ws[2048 + e] = g1 * g2;   // E1
        ws[3072 + e] = g2 * u;    // E2
    }
}

// --- k_main: one wave per 2 tokens; 7 const vectors staged in LDS (28 KB);
// x loads issued before staging so they overlap it; single 17-value shuffle
// round (12 per-token moments + 5 token-independent scalars).
__global__ __launch_bounds__(256) void k_main(const float* __restrict__ x,
                                              const float* __restrict__ g1v,
                                              const float* __restrict__ g2v,
                                              const float* __restrict__ b2v,
                                              const float* __restrict__ ws,
                                              float* __restrict__ out) {
    // LDS layout: attn 0 | u 1024 | g1 2048 | E1 3072 | E2 4096 | g2 5120 | b2 6144
    __shared__ float sm[7 * 1024];
    int tid = threadIdx.x;
    int pair = blockIdx.x * 4 + (tid >> 6);
    int lane = tid & 63;
    const int base0 = (pair * 2) * EMBED;
    const int base1 = base0 + EMBED;

    // Issue streaming x loads first (NT, stay in flight during LDS staging)
    f32x4 xv0[4], xv1[4];
    #pragma unroll
    for (int c = 0; c < 4; ++c) {
        int off = c * 256 + lane * 4;
        xv0[c] = __builtin_nontemporal_load((const f32x4*)(x + base0 + off));
        xv1[c] = __builtin_nontemporal_load((const f32x4*)(x + base1 + off));
    }

    // Stage 7 const vectors: each thread covers floats [tid*4, tid*4+4)
    {
        int o = tid * 4;
        *(f32x4*)(sm + o)        = *(const f32x4*)(ws + o);          // attn
        *(f32x4*)(sm + 1024 + o) = *(const f32x4*)(ws + 1024 + o);   // u
        *(f32x4*)(sm + 2048 + o) = *(const f32x4*)(g1v + o);         // g1
        *(f32x4*)(sm + 3072 + o) = *(const f32x4*)(ws + 2048 + o);   // E1
        *(f32x4*)(sm + 4096 + o) = *(const f32x4*)(ws + 3072 + o);   // E2
        *(f32x4*)(sm + 5120 + o) = *(const f32x4*)(g2v + o);         // g2
        *(f32x4*)(sm + 6144 + o) = *(const f32x4*)(b2v + o);         // b2
    }
    __syncthreads();

    // pass 1 (both tokens): y = x + attn; w = g1*y; 6 moments each + 5 scalars
    float y0[16], y1[16];
    float s_0 = 0.f, s2_0 = 0.f, p_0 = 0.f, p2_0 = 0.f, q_0 = 0.f, pu_0 = 0.f;
    float s_1 = 0.f, s2_1 = 0.f, p_1 = 0.f, p2_1 = 0.f, q_1 = 0.f, pu_1 = 0.f;
    float sg = 0.f, su = 0.f, sg2 = 0.f, sgu = 0.f, su2 = 0.f;
    #pragma unroll
    for (int c = 0; c < 4; ++c) {
        int off = c * 256 + lane * 4;
        f32x4 av = *(const f32x4*)(sm + off);
        f32x4 gv = *(const f32x4*)(sm + 2048 + off);
        f32x4 uv = *(const f32x4*)(sm + 1024 + off);
        #pragma unroll
        for (int k = 0; k < 4; ++k) {
            float yy0 = xv0[c][k] + av[k];
            float yy1 = xv1[c][k] + av[k];
            float w0 = gv[k] * yy0;
            float w1 = gv[k] * yy1;
            y0[c * 4 + k] = yy0;
            y1[c * 4 + k] = yy1;
            s_0 += yy0;            s_1 += yy1;
            s2_0 = fmaf(yy0, yy0, s2_0);  s2_1 = fmaf(yy1, yy1, s2_1);
            p_0 += w0;             p_1 += w1;
            p2_0 = fmaf(w0, w0, p2_0);    p2_1 = fmaf(w1, w1, p2_1);
            q_0 = fmaf(gv[k], w0, q_0);   q_1 = fmaf(gv[k], w1, q_1);
            pu_0 = fmaf(w0, uv[k], pu_0); pu_1 = fmaf(w1, uv[k], pu_1);
            sg += gv[k];
            su += uv[k];
            sg2 = fmaf(gv[k], gv[k], sg2);
            sgu = fmaf(gv[k], uv[k], sgu);
            su2 = fmaf(uv[k], uv[k], su2);
        }
    }

    // one reduction round, 17 values
    #pragma unroll
    for (int m = 32; m >= 1; m >>= 1) {
        s_0 += __shfl_xor(s_0, m, 64);   s_1 += __shfl_xor(s_1, m, 64);
        s2_0 += __shfl_xor(s2_0, m, 64); s2_1 += __shfl_xor(s2_1, m, 64);
        p_0 += __shfl_xor(p_0, m, 64);   p_1 += __shfl_xor(p_1, m, 64);
        p2_0 += __shfl_xor(p2_0, m, 64); p2_1 += __shfl_xor(p2_1, m, 64);
        q_0 += __shfl_xor(q_0, m, 64);   q_1 += __shfl_xor(q_1, m, 64);
        pu_0 += __shfl_xor(pu_0, m, 64); pu_1 += __shfl_xor(pu_1, m, 64);
        sg += __shfl_xor(sg, m, 64);
        su += __shfl_xor(su, m, 64);
        sg2 += __shfl_xor(sg2, m, 64);
        sgu += __shfl_xor(sgu, m, 64);
        su2 += __shfl_xor(su2, m, 64);
    }
    float Sg1 = sg, Su = su, Sg12 = sg2, Sg1u = sgu, Su2 = su2;

    const float rN = 1.f / EMBED;
    float m1_0 = s_0 * rN;
    float m1_1 = s_1 * rN;
    float rs1_0 = rsqrtf(s2_0 * rN - m1_0 * m1_0 + EPS);
    float rs1_1 = rsqrtf(s2_1 * rN - m1_1 * m1_1 + EPS);
    float t_0 = rs1_0 * (p_0 - m1_0 * Sg1) + Su;
    float t_1 = rs1_1 * (p_1 - m1_1 * Sg1) + Su;
    float t2_0 = rs1_0 * rs1_0 * (p2_0 - 2.f * m1_0 * q_0 + m1_0 * m1_0 * Sg12)
               + 2.f * rs1_0 * (pu_0 - m1_0 * Sg1u) + Su2;
    float t2_1 = rs1_1 * rs1_1 * (p2_1 - 2.f * m1_1 * q_1 + m1_1 * m1_1 * Sg12)
               + 2.f * rs1_1 * (pu_1 - m1_1 * Sg1u) + Su2;
    float m2_0 = t_0 * rN;
    float m2_1 = t_1 * rN;
    float rs2_0 = rsqrtf(t2_0 * rN - m2_0 * m2_0 + EPS);
    float rs2_1 = rsqrtf(t2_1 * rN - m2_1 * m2_1 + EPS);

    float A0 = rs1_0 * rs2_0, B0 = m2_0 * rs2_0;
    float A1 = rs1_1 * rs2_1, B1 = m2_1 * rs2_1;

    #pragma unroll
    for (int c = 0; c < 4; ++c) {
        int off = c * 256 + lane * 4;
        f32x4 e1 = *(const f32x4*)(sm + 3072 + off);
        f32x4 e2 = *(const f32x4*)(sm + 4096 + off);
        f32x4 g2 = *(const f32x4*)(sm + 5120 + off);
        f32x4 b2 = *(const f32x4*)(sm + 6144 + off);
        f32x4 o0, o1;
        #pragma unroll
        for (int k = 0; k < 4; ++k) {
            float c0 = fmaf(rs2_0, e2[k], fmaf(-B0, g2[k], b2[k]));
            float c1 = fmaf(rs2_1, e2[k], fmaf(-B1, g2[k], b2[k]));
            o0[k] = fmaf(A0 * e1[k], y0[c * 4 + k] - m1_0, c0);
            o1[k] = fmaf(A1 * e1[k], y1[c * 4 + k] - m1_1, c1);
        }
        __builtin_nontemporal_store(o0, (f32x4*)(out + base0 + off));
        __builtin_nontemporal_store(o1, (f32x4*)(out + base1 + off));
    }
}

extern "C" void kernel_launch(void* const* d_in, const int* in_sizes, int n_in,
                              void* d_out, int out_size, void* d_ws, size_t ws_size,
                              hipStream_t stream) {
    // 0:x 1:wq 2:wk 3:wv 4:w_mix 5:attn_params 6:w1 7:w2 8:w_out 9:ffn_params
    // 10:ln1_g 11:ln1_b 12:ln2_g 13:ln2_b
    const float* x      = (const float*)d_in[0];
    const float* w_mix  = (const float*)d_in[4];
    const float* attn_p = (const float*)d_in[5];
    const float* w2     = (const float*)d_in[7];
    const float* w_out  = (const float*)d_in[8];
    const float* ffn_p  = (const float*)d_in[9];
    const float* ln1_g  = (const float*)d_in[10];
    const float* ln1_b  = (const float*)d_in[11];
    const float* ln2_g  = (const float*)d_in[12];
    const float* ln2_b  = (const float*)d_in[13];
    float* out = (float*)d_out;
    float* ws  = (float*)d_ws;

    k_hidden<<<FFN_DIM / 256, 256, 0, stream>>>(w2, ffn_p, ws + 4224);
    k_const<<<EMBED / 4, 256, 0, stream>>>(w_mix, attn_p, w_out,
                                           ln1_g, ln1_b, ln2_g, ws);
    k_main<<<TOKENS / 8, 256, 0, stream>>>(x, ln1_g, ln2_g, ln2_b, ws, out);
}